// Round 8
// baseline (233.306 us; speedup 1.0000x reference)
//
#include <hip/hip_runtime.h>
#include <cmath>

// MultimodalCrossAttention on MI355X (gfx950), bf16 MFMA pipeline.
// B=2, Sx=Sc=2048, D_MODEL=1024, H=16, hd=64.

typedef __bf16 bf16x8 __attribute__((ext_vector_type(8)));
typedef __bf16 bf16x4 __attribute__((ext_vector_type(4)));
typedef float f32x4 __attribute__((ext_vector_type(4)));
typedef float f32x16 __attribute__((ext_vector_type(16)));
typedef unsigned u32x4v __attribute__((ext_vector_type(4)));

#define MFMA(A, B, C) __builtin_amdgcn_mfma_f32_16x16x32_bf16(A, B, C, 0, 0, 0)
#define MFMA32(A, B, C) __builtin_amdgcn_mfma_f32_32x32x16_bf16(A, B, C, 0, 0, 0)
#define GLL16(g, l)                                                        \
  __builtin_amdgcn_global_load_lds(                                        \
      (const __attribute__((address_space(1))) unsigned int*)(g),          \
      (__attribute__((address_space(3))) unsigned int*)(l), 16, 0, 0)

#define VMCNT(N) asm volatile("s_waitcnt vmcnt(" #N ")" ::: "memory")
#define BARM() asm volatile("s_barrier" ::: "memory")
#define LGKM0() asm volatile("s_waitcnt lgkmcnt(0)" ::: "memory")

// ---------------- fused fp32 -> bf16 convert, 2 float4/thread ----------------
__global__ __launch_bounds__(256) void cvt_all_kernel(
    const float* __restrict__ x, const float* __restrict__ ctx,
    const float* __restrict__ Wq, const float* __restrict__ Wv,
    const float* __restrict__ Wo, __bf16* __restrict__ xb, __bf16* __restrict__ cb,
    __bf16* __restrict__ Wqb, __bf16* __restrict__ Wvb, __bf16* __restrict__ Wob) {
  int base = blockIdx.x * 512 + threadIdx.x;
  const float* src;
  __bf16* dst;
  int off;
  if (base < 1048576) { src = x; dst = xb; off = 0; }
  else if (base < 2097152) { src = ctx; dst = cb; off = 1048576; }
  else if (base < 2359296) { src = Wq; dst = Wqb; off = 2097152; }
  else if (base < 2621440) { src = Wv; dst = Wvb; off = 2359296; }
  else { src = Wo; dst = Wob; off = 2621440; }
#pragma unroll
  for (int jj = 0; jj < 2; jj++) {
    int j = base - off + jj * 256;
    float4 f = ((const float4*)src)[j];
    bf16x4 o;
    o[0] = (__bf16)f.x; o[1] = (__bf16)f.y; o[2] = (__bf16)f.z; o[3] = (__bf16)f.w;
    ((bf16x4*)dst)[j] = o;
  }
}

// ---------------- Projection GEMM: 256x256, 8-phase schedule (proven round 6) ----------------
__global__ __launch_bounds__(512, 2) void gemm_proj(const __bf16* __restrict__ A0,
                                                    const __bf16* __restrict__ W0,
                                                    void* __restrict__ outQ,
                                                    void* __restrict__ outK,
                                                    void* __restrict__ outV) {
  const int tid = threadIdx.x;
  const int wave = tid >> 6, lane = tid & 63, quad = lane >> 4, l15 = lane & 15;
  const int wm = wave >> 2, wn = wave & 3;

  const int id = blockIdx.x;
  int m0, n0;
  const __bf16* A;
  const __bf16* W;
  bool vmode;
  if (id < 128) {                        // QK: A = xb||cb (8192 rows), W = Wq
    const int xcd = id & 7, j = id >> 3; // j 0..15
    m0 = (xcd * 4 + (j & 3)) * 256;
    n0 = (j >> 2) * 256;
    A = A0;
    W = W0;
    vmode = false;
  } else {                               // V: A = cb (4096 rows), W = Wv
    const int vid = id - 128;
    const int xcd = vid & 7, j = vid >> 3;  // j 0..7
    m0 = (xcd * 2 + (j & 1)) * 256;
    n0 = (j >> 1) * 256;
    A = A0 + (size_t)4096 * 1024;
    W = W0 + (size_t)1024 * 1024;
    vmode = true;
  }

  __shared__ __attribute__((aligned(16))) __bf16 As[2][2][8192];  // 64KB
  __shared__ __attribute__((aligned(16))) __bf16 Bs[2][2][8192];  // 64KB

  const int srow = tid >> 2;
  const int kcg = (tid & 3) ^ (srow & 3);
  const size_t aoff0 = (size_t)srow * 1024 + kcg * 8;
  const size_t aoff1 = (size_t)(srow + 128) * 1024 + kcg * 8;
  const __bf16* Ag = A + (size_t)m0 * 1024;
  const __bf16* Wg = W + (size_t)n0 * 1024;
  const int ldst0 = wave * 512;
  const int ldst1 = 4096 + wave * 512;

  auto stageA = [&](int slot, int kh, int kel) {
    GLL16(Ag + aoff0 + kel, &As[slot][kh][ldst0]);
    GLL16(Ag + aoff1 + kel, &As[slot][kh][ldst1]);
  };
  auto stageB = [&](int slot, int kh, int kel) {
    GLL16(Wg + aoff0 + kel, &Bs[slot][kh][ldst0]);
    GLL16(Wg + aoff1 + kel, &Bs[slot][kh][ldst1]);
  };

  const int xk = (quad ^ (l15 & 3)) * 8;
  int afo[8], bfo[4];
#pragma unroll
  for (int mf = 0; mf < 8; mf++) afo[mf] = (wm * 128 + mf * 16 + l15) * 32 + xk;
#pragma unroll
  for (int nf = 0; nf < 4; nf++) bfo[nf] = (wn * 64 + nf * 16 + l15) * 32 + xk;

  f32x4 acc[8][4] = {};
  bf16x8 bf[4], af[4];

  auto loadB = [&](int slot, int kh) {
#pragma unroll
    for (int nf = 0; nf < 4; nf++) bf[nf] = *(const bf16x8*)&Bs[slot][kh][bfo[nf]];
  };
  auto loadA = [&](int slot, int kh, int mfg) {
#pragma unroll
    for (int mf = 0; mf < 4; mf++)
      af[mf] = *(const bf16x8*)&As[slot][kh][afo[mfg * 4 + mf]];
  };
  auto mfma16 = [&](int mfg) {
    __builtin_amdgcn_s_setprio(1);
#pragma unroll
    for (int mf = 0; mf < 4; mf++)
#pragma unroll
      for (int nf = 0; nf < 4; nf++)
        acc[mfg * 4 + mf][nf] = MFMA(af[mf], bf[nf], acc[mfg * 4 + mf][nf]);
    __builtin_amdgcn_s_setprio(0);
  };

  stageA(0, 0, 0);  stageB(0, 0, 0);
  stageA(0, 1, 32); stageB(0, 1, 32);
  stageA(1, 0, 64); stageB(1, 0, 64);
  VMCNT(8); BARM();

#pragma unroll 1
  for (int j = 0; j < 7; j++) {
    const int kb = j * 128;
    loadB(0, 0); loadA(0, 0, 0); stageA(1, 1, kb + 96);
    BARM(); LGKM0(); mfma16(0); BARM();
    loadA(0, 0, 1); stageB(1, 1, kb + 96);
    BARM(); LGKM0(); mfma16(1); VMCNT(8); BARM();
    loadB(0, 1); loadA(0, 1, 0); stageA(0, 0, kb + 128);
    BARM(); LGKM0(); mfma16(0); BARM();
    loadA(0, 1, 1); stageB(0, 0, kb + 128);
    BARM(); LGKM0(); mfma16(1); VMCNT(8); BARM();
    loadB(1, 0); loadA(1, 0, 0); stageA(0, 1, kb + 160);
    BARM(); LGKM0(); mfma16(0); BARM();
    loadA(1, 0, 1); stageB(0, 1, kb + 160);
    BARM(); LGKM0(); mfma16(1); VMCNT(8); BARM();
    loadB(1, 1); loadA(1, 1, 0); stageA(1, 0, kb + 192);
    BARM(); LGKM0(); mfma16(0); BARM();
    loadA(1, 1, 1); stageB(1, 0, kb + 192);
    BARM(); LGKM0(); mfma16(1); VMCNT(8); BARM();
  }
  {
    loadB(0, 0); loadA(0, 0, 0); stageA(1, 1, 992);
    BARM(); LGKM0(); mfma16(0); BARM();
    loadA(0, 0, 1); stageB(1, 1, 992);
    BARM(); LGKM0(); mfma16(1); VMCNT(8); BARM();
    loadB(0, 1); loadA(0, 1, 0);
    BARM(); LGKM0(); mfma16(0); BARM();
    loadA(0, 1, 1);
    BARM(); LGKM0(); mfma16(1); VMCNT(4); BARM();
    loadB(1, 0); loadA(1, 0, 0);
    BARM(); LGKM0(); mfma16(0); BARM();
    loadA(1, 0, 1);
    BARM(); LGKM0(); mfma16(1); VMCNT(0); BARM();
    loadB(1, 1); loadA(1, 1, 0);
    BARM(); LGKM0(); mfma16(0); BARM();
    loadA(1, 1, 1);
    BARM(); LGKM0(); mfma16(1);
  }

  if (!vmode) {
    const int isK = (m0 >= 4096);
    __bf16* O = (__bf16*)(isK ? outK : outQ);
    const float qsc = isK ? 1.0f : 0.18033688f;  // 0.125*log2(e) folded into Q
    const int mb = m0 & 4095;
#pragma unroll
    for (int nf = 0; nf < 4; nf++) {
      const int n = n0 + wn * 64 + nf * 16 + l15;
      const int h = n >> 6, d = n & 63, p = d >> 1;
      const float invf_rev =
          __builtin_amdgcn_exp2f(-((float)p * 0.41524101f + 2.6514961f));
#pragma unroll
      for (int mf = 0; mf < 8; mf++) {
#pragma unroll
        for (int r = 0; r < 4; r++) {
          const int row = mb + wm * 128 + mf * 16 + quad * 4 + r;
          const int s = row & 2047, b = row >> 11;
          float v = acc[mf][nf][r];
          float pv = __shfl_xor(v, 1, 64);
          float fr = __builtin_amdgcn_fractf((float)s * invf_rev);
          float sn = __builtin_amdgcn_sinf(fr);
          float cs = __builtin_amdgcn_cosf(fr);
          float res = (lane & 1) ? (pv * sn + v * cs) : (v * cs - pv * sn);
          O[((size_t)(b * 16 + h) * 2048 + s) * 64 + d] = (__bf16)(res * qsc);
        }
      }
    }
  } else {
    __bf16* O = (__bf16*)outV;
#pragma unroll
    for (int nf = 0; nf < 4; nf++) {
      const int n = n0 + wn * 64 + nf * 16 + l15;
      const int h = n >> 6, d = n & 63;
#pragma unroll
      for (int mf = 0; mf < 8; mf++) {
        const int rowb = m0 + wm * 128 + mf * 16 + quad * 4;
        const int s = rowb & 2047, b = rowb >> 11;
        bf16x4 o;
#pragma unroll
        for (int r = 0; r < 4; r++) o[r] = (__bf16)acc[mf][nf][r];
        *(bf16x4*)(O + ((size_t)(b * 16 + h) * 64 + d) * 2048 + s) = o;
      }
    }
  }
}

// ---------------- Out-proj GEMM: 128x64 tile, triple-buffered, XCD-swizzled ----------------
// (round-2 proven version)
__global__ __launch_bounds__(256) void gemm_out(const __bf16* __restrict__ A,
                                                const __bf16* __restrict__ W,
                                                float* __restrict__ O,
                                                const float* __restrict__ bias) {
  const int tid = threadIdx.x;
  const int wave = tid >> 6, lane = tid & 63, quad = lane >> 4, l15 = lane & 15;
  const int mw = wave >> 1, nw = wave & 1;
  const int id = blockIdx.x;
  const int xcd = id & 7, j = id >> 3;       // j 0..63
  const int m0 = (xcd * 4 + (j & 3)) * 128;  // 32 m-tiles
  const int n0 = (j >> 2) * 64;              // 16 n-tiles

  __shared__ __attribute__((aligned(16))) __bf16 As[3][4096];  // 24KB
  __shared__ __attribute__((aligned(16))) __bf16 Ws[3][2048];  // 12KB

  int goff[2];
#pragma unroll
  for (int jj = 0; jj < 2; jj++) {
    const int s = jj * 256 + tid;
    const int row = s >> 2;
    const int kcg = (s & 3) ^ ((row >> 1) & 3);
    goff[jj] = row * 1024 + kcg * 8;
  }
  const int wrow = tid >> 2;
  const int wkcg = (tid & 3) ^ ((wrow >> 1) & 3);
  const int goffw = wrow * 1024 + wkcg * 8;

  const __bf16* Ag = A + (size_t)m0 * 1024;
  const __bf16* Wg = W + (size_t)n0 * 1024;
  const int ldsoff0 = wave * 512;
  const int ldsoff1 = 2048 + wave * 512;

  const int sw = (l15 >> 1) & 3;
  int afoff[4], wfoff[2];
#pragma unroll
  for (int t = 0; t < 4; t++)
    afoff[t] = (mw * 64 + t * 16 + l15) * 32 + (quad ^ sw) * 8;
#pragma unroll
  for (int t = 0; t < 2; t++)
    wfoff[t] = (nw * 32 + t * 16 + l15) * 32 + (quad ^ sw) * 8;

  f32x4 acc[4][2] = {};

  auto stage = [&](int buf, int k0) {
    GLL16(Ag + goff[0] + k0, &As[buf][ldsoff0]);
    GLL16(Ag + goff[1] + k0, &As[buf][ldsoff1]);
    GLL16(Wg + goffw + k0, &Ws[buf][ldsoff0]);
  };
  auto compute = [&](int buf) {
    bf16x8 af[4], wf[2];
#pragma unroll
    for (int t = 0; t < 4; t++) af[t] = *(const bf16x8*)&As[buf][afoff[t]];
#pragma unroll
    for (int t = 0; t < 2; t++) wf[t] = *(const bf16x8*)&Ws[buf][wfoff[t]];
#pragma unroll
    for (int mt = 0; mt < 4; mt++)
#pragma unroll
      for (int nt = 0; nt < 2; nt++) acc[mt][nt] = MFMA(af[mt], wf[nt], acc[mt][nt]);
  };

  stage(0, 0);
  stage(1, 32);
  int buf = 0;
  for (int c = 0; c < 32; c++) {
    __syncthreads();
    if (c + 2 < 32) {
      int nb = buf + 2;
      if (nb >= 3) nb -= 3;
      stage(nb, (c + 2) * 32);
    }
    compute(buf);
    buf = (buf == 2) ? 0 : buf + 1;
  }

#pragma unroll
  for (int nt = 0; nt < 2; nt++) {
    const int n = n0 + nw * 32 + nt * 16 + l15;
    const float bv = bias[n];
#pragma unroll
    for (int mt = 0; mt < 4; mt++) {
#pragma unroll
      for (int r = 0; r < 4; r++) {
        const int row = m0 + mw * 64 + mt * 16 + quad * 4 + r;
        O[(size_t)row * 1024 + n] = acc[mt][nt][r] + bv;
      }
    }
  }
}

// ---------------- Flash attention: 32x32 MFMA, K slot-major LDS, V global->reg ----------------
// R7 conflict-free K layout kept. V no longer staged through LDS at all: each
// wave loads its 4 B-operand fragments per 64-k half DIRECTLY from vt (L2-
// resident) into registers, one compute ahead (T14 issue-early/consume-late),
// ping-pong between two statically-named reg sets (rule #20). LDS reads/iter
// 16 -> 8 (the dominant CU-shared pipe, ~20us -> ~10us); LDS 64KB -> 34KB.
__global__ __launch_bounds__(512, 4) void attn_kernel(const __bf16* __restrict__ Q,
                                                      const __bf16* __restrict__ K,
                                                      const __bf16* __restrict__ Vt,
                                                      __bf16* __restrict__ Aout) {
  const int tid = threadIdx.x;
  const int wave = tid >> 6, lane = tid & 63;
  const int l31 = lane & 31, hi = lane >> 5;
  const int qg = wave >> 1, kg = wave & 1;
  const int id = blockIdx.x;
  const int j = id >> 3;
  const int bh = ((id & 7) << 2) | (j & 3);
  const int q0 = (j >> 2) << 7;

  const __bf16* Qb = Q + (size_t)bh * (2048 * 64);
  const __bf16* Kb = K + (size_t)bh * (2048 * 64);
  const __bf16* Vb = Vt + (size_t)bh * (64 * 2048);

  __shared__ __attribute__((aligned(16))) __bf16 Kbuf[4][4096];  // 32KB
  __shared__ __attribute__((aligned(16))) float Lred[512];       // 2KB

  bf16x8 qf[4];
  {
    const __bf16* qp = Qb + (size_t)(q0 + qg * 32 + l31) * 64 + hi * 8;
#pragma unroll
    for (int i = 0; i < 4; i++) qf[i] = *(const bf16x8*)(qp + i * 16);
  }

  // K slot-major staging (proven R7): wave w = slot w; lane l = row l.
  const __bf16* kgp = Kb + lane * 64 + wave * 8;
  const int klds = wave * 512;

  // K frag: row rk = kg*32+l31, slot = 2i+hi -> elem off = slot*512 + rk*8
  int koff[4];
  {
    const int rk = kg * 32 + l31;
#pragma unroll
    for (int i = 0; i < 4; i++) koff[i] = (2 * i + hi) * 512 + rk * 8;
  }
  // V frag global base: addr = Vb + (dt*32+l31)*2048 + ktb + (kg*4+hi)*8 + ks*16
  const __bf16* vgb = Vb + (size_t)l31 * 2048 + (kg * 4 + hi) * 8;

  f32x4 rs4 = {};
  f32x16 oacc[2] = {};

  auto stageK = [&](int buf, int kt) { GLL16(kgp + kt * 64, &Kbuf[buf][klds]); };

  auto loadV = [&](bf16x8 (&vf)[2][2], int ktb) {
#pragma unroll
    for (int dt = 0; dt < 2; dt++)
#pragma unroll
      for (int ks = 0; ks < 2; ks++)
        vf[dt][ks] = *(const bf16x8*)(vgb + (size_t)dt * 32 * 2048 + ktb + ks * 16);
  };

  auto compute = [&](int buf, const bf16x8 (&vf)[2][2]) {
    f32x16 s = {};
#pragma unroll
    for (int i = 0; i < 4; i++) {
      bf16x8 kf = *(const bf16x8*)&Kbuf[buf][koff[i]];
      s = MFMA32(kf, qf[i], s);
    }
    float pe[16];
#pragma unroll
    for (int r = 0; r < 16; r++) pe[r] = __builtin_amdgcn_exp2f(s[r]);
#pragma unroll
    for (int r = 0; r < 16; r++) rs4[r & 3] += pe[r];
    bf16x8 pa[2];
#pragma unroll
    for (int sl = 0; sl < 2; sl++) {
      unsigned wa, wb, wc, wd;
      asm("v_cvt_pk_bf16_f32 %0, %1, %2" : "=v"(wa) : "v"(pe[8 * sl + 0]), "v"(pe[8 * sl + 1]));
      asm("v_cvt_pk_bf16_f32 %0, %1, %2" : "=v"(wb) : "v"(pe[8 * sl + 4]), "v"(pe[8 * sl + 5]));
      asm("v_cvt_pk_bf16_f32 %0, %1, %2" : "=v"(wc) : "v"(pe[8 * sl + 2]), "v"(pe[8 * sl + 3]));
      asm("v_cvt_pk_bf16_f32 %0, %1, %2" : "=v"(wd) : "v"(pe[8 * sl + 6]), "v"(pe[8 * sl + 7]));
      asm("v_permlane32_swap_b32 %0, %1" : "+v"(wa), "+v"(wb));
      asm("v_permlane32_swap_b32 %0, %1" : "+v"(wc), "+v"(wd));
      u32x4v t;
      t[0] = wa; t[1] = wc; t[2] = wb; t[3] = wd;
      pa[sl] = __builtin_bit_cast(bf16x8, t);
    }
#pragma unroll
    for (int dt = 0; dt < 2; dt++)
#pragma unroll
      for (int ks = 0; ks < 2; ks++)
        oacc[dt] = MFMA32(pa[ks], vf[dt][ks], oacc[dt]);
  };

  bf16x8 vX[2][2], vY[2][2];
  loadV(vX, 0);
  stageK(0, 0);
  stageK(1, 64);
  for (int kt = 0; kt < 2048; kt += 128) {
    const int p = (kt >> 7) & 1;
    __syncthreads();
    if (kt + 128 < 2048) {
      stageK(2 * (p ^ 1), kt + 128);
      stageK(2 * (p ^ 1) + 1, kt + 192);
    }
    loadV(vY, kt + 64);              // consumed after compute of first half
    compute(2 * p, vX);
    if (kt + 128 < 2048) loadV(vX, kt + 128);  // next iter's first half
    compute(2 * p + 1, vY);
  }

  // ---- cross-kg reduction (Kbuf reused as f32 scratch) ----
  __syncthreads();
  float* Ored = (float*)&Kbuf[0][0];  // [4 qg][32 slot][64 lane] f32 = 32KB

  float lw = (rs4[0] + rs4[1]) + (rs4[2] + rs4[3]);
  lw += __shfl_xor(lw, 32, 64);
  Lred[wave * 64 + lane] = lw;
  if (kg == 1) {
#pragma unroll
    for (int dt = 0; dt < 2; dt++)
#pragma unroll
      for (int r = 0; r < 16; r++)
        Ored[(qg * 32 + dt * 16 + r) * 64 + lane] = oacc[dt][r];
  }
  __syncthreads();
  if (kg == 0) {
    const int b = bh >> 4, h = bh & 15;
#pragma unroll
    for (int r = 0; r < 16; r++) {
      const int qrow = (r & 3) + 8 * (r >> 2) + 4 * hi;
      const float lt =
          Lred[(qg * 2) * 64 + qrow] + Lred[(qg * 2 + 1) * 64 + qrow];
      const float inv = 1.f / lt;
      const int qAbs = q0 + qg * 32 + qrow;
#pragma unroll
      for (int dt = 0; dt < 2; dt++) {
        const float o = oacc[dt][r] + Ored[(qg * 32 + dt * 16 + r) * 64 + lane];
        Aout[((size_t)(b * 2048 + qAbs)) * 1024 + h * 64 + dt * 32 + l31] =
            (__bf16)(o * inv);
      }
    }
  }
}

extern "C" void kernel_launch(void* const* d_in, const int* in_sizes, int n_in,
                              void* d_out, int out_size, void* d_ws, size_t ws_size,
                              hipStream_t stream) {
  const float* x   = (const float*)d_in[0];
  const float* ctx = (const float*)d_in[1];
  const float* Wq  = (const float*)d_in[2];
  const float* Wv  = (const float*)d_in[3];
  const float* Wo  = (const float*)d_in[4];
  const float* bo  = (const float*)d_in[5];

  char* ws = (char*)d_ws;
  const size_t MB = 1024 * 1024;
  __bf16* xb   = (__bf16*)(ws + 0 * MB);   // [4096,1024]; contiguous with cb
  __bf16* cb   = (__bf16*)(ws + 8 * MB);   // [4096,1024]
  __bf16* Wqb  = (__bf16*)(ws + 16 * MB);  // contiguous with Wvb
  __bf16* Wvb  = (__bf16*)(ws + 18 * MB);
  __bf16* Wob  = (__bf16*)(ws + 20 * MB);
  __bf16* qh   = (__bf16*)(ws + 22 * MB);  // [b,h,s,d], pre-scaled by 0.18034
  __bf16* kh   = (__bf16*)(ws + 30 * MB);  // [b,h,s,d]
  __bf16* vt   = (__bf16*)(ws + 38 * MB);  // [b,h,d,s]
  __bf16* attn = xb;  // xb dead after QK projection

  cvt_all_kernel<<<5632, 256, 0, stream>>>(x, ctx, Wq, Wv, Wo, xb, cb, Wqb, Wvb, Wob);

  gemm_proj<<<192, 512, 0, stream>>>(xb, Wqb, (void*)qh, (void*)kh, (void*)vt);

  attn_kernel<<<512, 512, 0, stream>>>(qh, kh, vt, attn);

  gemm_out<<<512, 256, 0, stream>>>(attn, Wob, (float*)d_out, bo);
}

// Round 9
// 201.069 us; speedup vs baseline: 1.1603x; 1.1603x over previous
//
#include <hip/hip_runtime.h>
#include <cmath>

// MultimodalCrossAttention on MI355X (gfx950), bf16 MFMA pipeline.
// B=2, Sx=Sc=2048, D_MODEL=1024, H=16, hd=64.

typedef __bf16 bf16x8 __attribute__((ext_vector_type(8)));
typedef __bf16 bf16x4 __attribute__((ext_vector_type(4)));
typedef float f32x4 __attribute__((ext_vector_type(4)));
typedef float f32x16 __attribute__((ext_vector_type(16)));
typedef unsigned u32x4v __attribute__((ext_vector_type(4)));

#define MFMA(A, B, C) __builtin_amdgcn_mfma_f32_16x16x32_bf16(A, B, C, 0, 0, 0)
#define MFMA32(A, B, C) __builtin_amdgcn_mfma_f32_32x32x16_bf16(A, B, C, 0, 0, 0)
#define GLL16(g, l)                                                        \
  __builtin_amdgcn_global_load_lds(                                        \
      (const __attribute__((address_space(1))) unsigned int*)(g),          \
      (__attribute__((address_space(3))) unsigned int*)(l), 16, 0, 0)

#define VMCNT(N) asm volatile("s_waitcnt vmcnt(" #N ")" ::: "memory")
#define BARM() asm volatile("s_barrier" ::: "memory")
#define LGKM0() asm volatile("s_waitcnt lgkmcnt(0)" ::: "memory")

// ---------------- fused fp32 -> bf16 convert, 2 float4/thread ----------------
__global__ __launch_bounds__(256) void cvt_all_kernel(
    const float* __restrict__ x, const float* __restrict__ ctx,
    const float* __restrict__ Wq, const float* __restrict__ Wv,
    const float* __restrict__ Wo, __bf16* __restrict__ xb, __bf16* __restrict__ cb,
    __bf16* __restrict__ Wqb, __bf16* __restrict__ Wvb, __bf16* __restrict__ Wob) {
  int base = blockIdx.x * 512 + threadIdx.x;
  const float* src;
  __bf16* dst;
  int off;
  if (base < 1048576) { src = x; dst = xb; off = 0; }
  else if (base < 2097152) { src = ctx; dst = cb; off = 1048576; }
  else if (base < 2359296) { src = Wq; dst = Wqb; off = 2097152; }
  else if (base < 2621440) { src = Wv; dst = Wvb; off = 2359296; }
  else { src = Wo; dst = Wob; off = 2621440; }
#pragma unroll
  for (int jj = 0; jj < 2; jj++) {
    int j = base - off + jj * 256;
    float4 f = ((const float4*)src)[j];
    bf16x4 o;
    o[0] = (__bf16)f.x; o[1] = (__bf16)f.y; o[2] = (__bf16)f.z; o[3] = (__bf16)f.w;
    ((bf16x4*)dst)[j] = o;
  }
}

// ---------------- Projection GEMM: 256x256, 8-phase schedule (proven round 6) ----------------
__global__ __launch_bounds__(512, 2) void gemm_proj(const __bf16* __restrict__ A0,
                                                    const __bf16* __restrict__ W0,
                                                    void* __restrict__ outQ,
                                                    void* __restrict__ outK,
                                                    void* __restrict__ outV) {
  const int tid = threadIdx.x;
  const int wave = tid >> 6, lane = tid & 63, quad = lane >> 4, l15 = lane & 15;
  const int wm = wave >> 2, wn = wave & 3;

  const int id = blockIdx.x;
  int m0, n0;
  const __bf16* A;
  const __bf16* W;
  bool vmode;
  if (id < 128) {                        // QK: A = xb||cb (8192 rows), W = Wq
    const int xcd = id & 7, j = id >> 3; // j 0..15
    m0 = (xcd * 4 + (j & 3)) * 256;
    n0 = (j >> 2) * 256;
    A = A0;
    W = W0;
    vmode = false;
  } else {                               // V: A = cb (4096 rows), W = Wv
    const int vid = id - 128;
    const int xcd = vid & 7, j = vid >> 3;  // j 0..7
    m0 = (xcd * 2 + (j & 1)) * 256;
    n0 = (j >> 1) * 256;
    A = A0 + (size_t)4096 * 1024;
    W = W0 + (size_t)1024 * 1024;
    vmode = true;
  }

  __shared__ __attribute__((aligned(16))) __bf16 As[2][2][8192];  // 64KB
  __shared__ __attribute__((aligned(16))) __bf16 Bs[2][2][8192];  // 64KB

  const int srow = tid >> 2;
  const int kcg = (tid & 3) ^ (srow & 3);
  const size_t aoff0 = (size_t)srow * 1024 + kcg * 8;
  const size_t aoff1 = (size_t)(srow + 128) * 1024 + kcg * 8;
  const __bf16* Ag = A + (size_t)m0 * 1024;
  const __bf16* Wg = W + (size_t)n0 * 1024;
  const int ldst0 = wave * 512;
  const int ldst1 = 4096 + wave * 512;

  auto stageA = [&](int slot, int kh, int kel) {
    GLL16(Ag + aoff0 + kel, &As[slot][kh][ldst0]);
    GLL16(Ag + aoff1 + kel, &As[slot][kh][ldst1]);
  };
  auto stageB = [&](int slot, int kh, int kel) {
    GLL16(Wg + aoff0 + kel, &Bs[slot][kh][ldst0]);
    GLL16(Wg + aoff1 + kel, &Bs[slot][kh][ldst1]);
  };

  const int xk = (quad ^ (l15 & 3)) * 8;
  int afo[8], bfo[4];
#pragma unroll
  for (int mf = 0; mf < 8; mf++) afo[mf] = (wm * 128 + mf * 16 + l15) * 32 + xk;
#pragma unroll
  for (int nf = 0; nf < 4; nf++) bfo[nf] = (wn * 64 + nf * 16 + l15) * 32 + xk;

  f32x4 acc[8][4] = {};
  bf16x8 bf[4], af[4];

  auto loadB = [&](int slot, int kh) {
#pragma unroll
    for (int nf = 0; nf < 4; nf++) bf[nf] = *(const bf16x8*)&Bs[slot][kh][bfo[nf]];
  };
  auto loadA = [&](int slot, int kh, int mfg) {
#pragma unroll
    for (int mf = 0; mf < 4; mf++)
      af[mf] = *(const bf16x8*)&As[slot][kh][afo[mfg * 4 + mf]];
  };
  auto mfma16 = [&](int mfg) {
    __builtin_amdgcn_s_setprio(1);
#pragma unroll
    for (int mf = 0; mf < 4; mf++)
#pragma unroll
      for (int nf = 0; nf < 4; nf++)
        acc[mfg * 4 + mf][nf] = MFMA(af[mf], bf[nf], acc[mfg * 4 + mf][nf]);
    __builtin_amdgcn_s_setprio(0);
  };

  stageA(0, 0, 0);  stageB(0, 0, 0);
  stageA(0, 1, 32); stageB(0, 1, 32);
  stageA(1, 0, 64); stageB(1, 0, 64);
  VMCNT(8); BARM();

#pragma unroll 1
  for (int j = 0; j < 7; j++) {
    const int kb = j * 128;
    loadB(0, 0); loadA(0, 0, 0); stageA(1, 1, kb + 96);
    BARM(); LGKM0(); mfma16(0); BARM();
    loadA(0, 0, 1); stageB(1, 1, kb + 96);
    BARM(); LGKM0(); mfma16(1); VMCNT(8); BARM();
    loadB(0, 1); loadA(0, 1, 0); stageA(0, 0, kb + 128);
    BARM(); LGKM0(); mfma16(0); BARM();
    loadA(0, 1, 1); stageB(0, 0, kb + 128);
    BARM(); LGKM0(); mfma16(1); VMCNT(8); BARM();
    loadB(1, 0); loadA(1, 0, 0); stageA(0, 1, kb + 160);
    BARM(); LGKM0(); mfma16(0); BARM();
    loadA(1, 0, 1); stageB(0, 1, kb + 160);
    BARM(); LGKM0(); mfma16(1); VMCNT(8); BARM();
    loadB(1, 1); loadA(1, 1, 0); stageA(1, 0, kb + 192);
    BARM(); LGKM0(); mfma16(0); BARM();
    loadA(1, 1, 1); stageB(1, 0, kb + 192);
    BARM(); LGKM0(); mfma16(1); VMCNT(8); BARM();
  }
  {
    loadB(0, 0); loadA(0, 0, 0); stageA(1, 1, 992);
    BARM(); LGKM0(); mfma16(0); BARM();
    loadA(0, 0, 1); stageB(1, 1, 992);
    BARM(); LGKM0(); mfma16(1); VMCNT(8); BARM();
    loadB(0, 1); loadA(0, 1, 0);
    BARM(); LGKM0(); mfma16(0); BARM();
    loadA(0, 1, 1);
    BARM(); LGKM0(); mfma16(1); VMCNT(4); BARM();
    loadB(1, 0); loadA(1, 0, 0);
    BARM(); LGKM0(); mfma16(0); BARM();
    loadA(1, 0, 1);
    BARM(); LGKM0(); mfma16(1); VMCNT(0); BARM();
    loadB(1, 1); loadA(1, 1, 0);
    BARM(); LGKM0(); mfma16(0); BARM();
    loadA(1, 1, 1);
    BARM(); LGKM0(); mfma16(1);
  }

  if (!vmode) {
    const int isK = (m0 >= 4096);
    __bf16* O = (__bf16*)(isK ? outK : outQ);
    const float qsc = isK ? 1.0f : 0.18033688f;  // 0.125*log2(e) folded into Q
    const int mb = m0 & 4095;
#pragma unroll
    for (int nf = 0; nf < 4; nf++) {
      const int n = n0 + wn * 64 + nf * 16 + l15;
      const int h = n >> 6, d = n & 63, p = d >> 1;
      const float invf_rev =
          __builtin_amdgcn_exp2f(-((float)p * 0.41524101f + 2.6514961f));
#pragma unroll
      for (int mf = 0; mf < 8; mf++) {
#pragma unroll
        for (int r = 0; r < 4; r++) {
          const int row = mb + wm * 128 + mf * 16 + quad * 4 + r;
          const int s = row & 2047, b = row >> 11;
          float v = acc[mf][nf][r];
          float pv = __shfl_xor(v, 1, 64);
          float fr = __builtin_amdgcn_fractf((float)s * invf_rev);
          float sn = __builtin_amdgcn_sinf(fr);
          float cs = __builtin_amdgcn_cosf(fr);
          float res = (lane & 1) ? (pv * sn + v * cs) : (v * cs - pv * sn);
          O[((size_t)(b * 16 + h) * 2048 + s) * 64 + d] = (__bf16)(res * qsc);
        }
      }
    }
  } else {
    __bf16* O = (__bf16*)outV;
#pragma unroll
    for (int nf = 0; nf < 4; nf++) {
      const int n = n0 + wn * 64 + nf * 16 + l15;
      const int h = n >> 6, d = n & 63;
#pragma unroll
      for (int mf = 0; mf < 8; mf++) {
        const int rowb = m0 + wm * 128 + mf * 16 + quad * 4;
        const int s = rowb & 2047, b = rowb >> 11;
        bf16x4 o;
#pragma unroll
        for (int r = 0; r < 4; r++) o[r] = (__bf16)acc[mf][nf][r];
        *(bf16x4*)(O + ((size_t)(b * 16 + h) * 64 + d) * 2048 + s) = o;
      }
    }
  }
}

// ---------------- Out-proj GEMM: 256x128, 8-phase schedule (proj template clone) ----------------
// 8 waves (4M x 2N), per-wave 64x64 (4x4 16x16 frags). K = 16 tiles of 64 (2 kh of 32).
// LDS: A units [256][32] 16KB x4 = 64KB; B units [128][32] 8KB x4 = 32KB -> 96KB, 1 blk/CU.
// Per iter 12 GLL/wave (4 stageA x2 + 4 stageB x1); stage leads consume by 6 phases ->
// exactly 6 younger loads at each even-phase wait -> VMCNT(6); peel drains 6->3->0.
// Grid 128 = 16 m-tiles x 8 n-tiles, XCD-bijective (128%8==0).
__global__ __launch_bounds__(512, 2) void gemm_out(const __bf16* __restrict__ A,
                                                   const __bf16* __restrict__ W,
                                                   float* __restrict__ O,
                                                   const float* __restrict__ bias) {
  const int tid = threadIdx.x;
  const int wave = tid >> 6, lane = tid & 63, quad = lane >> 4, l15 = lane & 15;
  const int wm = wave >> 1, wn = wave & 1;
  const int id = blockIdx.x;
  const int xcd = id & 7, jj = id >> 3;     // jj 0..15
  const int m0 = (xcd * 2 + (jj & 1)) * 256;  // 16 m-tiles
  const int n0 = (jj >> 1) * 128;             // 8 n-tiles

  __shared__ __attribute__((aligned(16))) __bf16 As[2][2][8192];  // 64KB
  __shared__ __attribute__((aligned(16))) __bf16 Bs[2][2][4096];  // 32KB

  const int srow = tid >> 2;
  const int kcg = (tid & 3) ^ (srow & 3);
  const size_t aoff0 = (size_t)srow * 1024 + kcg * 8;
  const size_t aoff1 = (size_t)(srow + 128) * 1024 + kcg * 8;
  const __bf16* Ag = A + (size_t)m0 * 1024;
  const __bf16* Wg = W + (size_t)n0 * 1024;
  const int ldst0 = wave * 512;
  const int ldst1 = 4096 + wave * 512;

  auto stageA = [&](int slot, int kh, int kel) {
    GLL16(Ag + aoff0 + kel, &As[slot][kh][ldst0]);
    GLL16(Ag + aoff1 + kel, &As[slot][kh][ldst1]);
  };
  auto stageB = [&](int slot, int kh, int kel) {
    GLL16(Wg + aoff0 + kel, &Bs[slot][kh][ldst0]);  // 128 rows: srow<128 covers it
  };

  const int xk = (quad ^ (l15 & 3)) * 8;
  int afo[4], bfo[4];
#pragma unroll
  for (int mf = 0; mf < 4; mf++) afo[mf] = (wm * 64 + mf * 16 + l15) * 32 + xk;
#pragma unroll
  for (int nf = 0; nf < 4; nf++) bfo[nf] = (wn * 64 + nf * 16 + l15) * 32 + xk;

  f32x4 acc[4][4] = {};
  bf16x8 bf[4], af[2];

  auto loadB = [&](int slot, int kh) {
#pragma unroll
    for (int nf = 0; nf < 4; nf++) bf[nf] = *(const bf16x8*)&Bs[slot][kh][bfo[nf]];
  };
  auto loadA = [&](int slot, int kh, int mfg) {
#pragma unroll
    for (int mf = 0; mf < 2; mf++)
      af[mf] = *(const bf16x8*)&As[slot][kh][afo[mfg * 2 + mf]];
  };
  auto mfma8 = [&](int mfg) {
    __builtin_amdgcn_s_setprio(1);
#pragma unroll
    for (int mf = 0; mf < 2; mf++)
#pragma unroll
      for (int nf = 0; nf < 4; nf++)
        acc[mfg * 2 + mf][nf] = MFMA(af[mf], bf[nf], acc[mfg * 2 + mf][nf]);
    __builtin_amdgcn_s_setprio(0);
  };

  // prologue: first 6 units in consumption order (9 GLL); first pair done at vmcnt(6)
  stageA(0, 0, 0);  stageB(0, 0, 0);
  stageA(0, 1, 32); stageB(0, 1, 32);
  stageA(1, 0, 64); stageB(1, 0, 64);
  VMCNT(6); BARM();

#pragma unroll 1
  for (int j = 0; j < 7; j++) {
    const int kb = j * 128;
    loadB(0, 0); loadA(0, 0, 0); stageA(1, 1, kb + 96);
    BARM(); LGKM0(); mfma8(0); BARM();
    loadA(0, 0, 1); stageB(1, 1, kb + 96);
    BARM(); LGKM0(); mfma8(1); VMCNT(6); BARM();
    loadB(0, 1); loadA(0, 1, 0); stageA(0, 0, kb + 128);
    BARM(); LGKM0(); mfma8(0); BARM();
    loadA(0, 1, 1); stageB(0, 0, kb + 128);
    BARM(); LGKM0(); mfma8(1); VMCNT(6); BARM();
    loadB(1, 0); loadA(1, 0, 0); stageA(0, 1, kb + 160);
    BARM(); LGKM0(); mfma8(0); BARM();
    loadA(1, 0, 1); stageB(0, 1, kb + 160);
    BARM(); LGKM0(); mfma8(1); VMCNT(6); BARM();
    loadB(1, 1); loadA(1, 1, 0); stageA(1, 0, kb + 192);
    BARM(); LGKM0(); mfma8(0); BARM();
    loadA(1, 1, 1); stageB(1, 0, kb + 192);
    BARM(); LGKM0(); mfma8(1); VMCNT(6); BARM();
  }
  // peel j=7: stages only in ph1/ph2; waits 6 -> 3 -> 0
  {
    loadB(0, 0); loadA(0, 0, 0); stageA(1, 1, 992);
    BARM(); LGKM0(); mfma8(0); BARM();
    loadA(0, 0, 1); stageB(1, 1, 992);
    BARM(); LGKM0(); mfma8(1); VMCNT(6); BARM();
    loadB(0, 1); loadA(0, 1, 0);
    BARM(); LGKM0(); mfma8(0); BARM();
    loadA(0, 1, 1);
    BARM(); LGKM0(); mfma8(1); VMCNT(3); BARM();
    loadB(1, 0); loadA(1, 0, 0);
    BARM(); LGKM0(); mfma8(0); BARM();
    loadA(1, 0, 1);
    BARM(); LGKM0(); mfma8(1); VMCNT(0); BARM();
    loadB(1, 1); loadA(1, 1, 0);
    BARM(); LGKM0(); mfma8(0); BARM();
    loadA(1, 1, 1);
    BARM(); LGKM0(); mfma8(1);
  }

  // Epilogue: C/D per 16x16 frag: row = quad*4+r, col = l15.
#pragma unroll
  for (int nf = 0; nf < 4; nf++) {
    const int n = n0 + wn * 64 + nf * 16 + l15;
    const float bv = bias[n];
#pragma unroll
    for (int mf = 0; mf < 4; mf++) {
#pragma unroll
      for (int r = 0; r < 4; r++) {
        const int row = m0 + wm * 64 + mf * 16 + quad * 4 + r;
        O[(size_t)row * 1024 + n] = acc[mf][nf][r] + bv;
      }
    }
  }
}

// ---------------- Flash attention: 32x32 MFMA, in-register P (proven round 6, 50.4us) ----------------
__global__ __launch_bounds__(512, 4) void attn_kernel(const __bf16* __restrict__ Q,
                                                      const __bf16* __restrict__ K,
                                                      const __bf16* __restrict__ Vt,
                                                      __bf16* __restrict__ Aout) {
  const int tid = threadIdx.x;
  const int wave = tid >> 6, lane = tid & 63;
  const int l31 = lane & 31, hi = lane >> 5;
  const int qg = wave >> 1, kg = wave & 1;
  const int id = blockIdx.x;
  const int j = id >> 3;
  const int bh = ((id & 7) << 2) | (j & 3);
  const int q0 = (j >> 2) << 7;

  const __bf16* Qb = Q + (size_t)bh * (2048 * 64);
  const __bf16* Kb = K + (size_t)bh * (2048 * 64);
  const __bf16* Vb = Vt + (size_t)bh * (64 * 2048);

  __shared__ __attribute__((aligned(16))) __bf16 Kbuf[4][4096];  // 32KB
  __shared__ __attribute__((aligned(16))) __bf16 Vbuf[4][4096];  // 32KB

  bf16x8 qf[4];
  {
    const __bf16* qp = Qb + (size_t)(q0 + qg * 32 + l31) * 64 + hi * 8;
#pragma unroll
    for (int i = 0; i < 4; i++) qf[i] = *(const bf16x8*)(qp + i * 16);
  }

  const int s0 = wave * 64 + lane;
  const int r0 = s0 >> 3, c0 = (s0 & 7) ^ (r0 & 7);
  const __bf16* kgp = Kb + r0 * 64 + c0 * 8;
  const __bf16* vgp = Vb + r0 * 2048 + c0 * 8;
  const int klds = wave * 512;

  int koff[4];
  {
    const int rk = kg * 32 + l31;
#pragma unroll
    for (int i = 0; i < 4; i++) koff[i] = rk * 64 + (((2 * i + hi) ^ (rk & 7)) * 8);
  }
  int voff[2][2];
#pragma unroll
  for (int dt = 0; dt < 2; dt++) {
    const int rv = dt * 32 + l31;
#pragma unroll
    for (int ks = 0; ks < 2; ks++)
      voff[dt][ks] = rv * 64 + (((kg * 4 + ks * 2 + hi) ^ (rv & 7)) * 8);
  }

  f32x4 rs4 = {};
  f32x16 oacc[2] = {};

  auto stage = [&](int buf, int kt) {
    GLL16(kgp + kt * 64, &Kbuf[buf][klds]);
    GLL16(vgp + kt, &Vbuf[buf][klds]);
  };

  auto compute = [&](int buf) {
    f32x16 s = {};
#pragma unroll
    for (int i = 0; i < 4; i++) {
      bf16x8 kf = *(const bf16x8*)&Kbuf[buf][koff[i]];
      s = MFMA32(kf, qf[i], s);
    }
    float pe[16];
#pragma unroll
    for (int r = 0; r < 16; r++) pe[r] = __builtin_amdgcn_exp2f(s[r]);
#pragma unroll
    for (int r = 0; r < 16; r++) rs4[r & 3] += pe[r];
    bf16x8 pa[2];
#pragma unroll
    for (int sl = 0; sl < 2; sl++) {
      unsigned wa, wb, wc, wd;
      asm("v_cvt_pk_bf16_f32 %0, %1, %2" : "=v"(wa) : "v"(pe[8 * sl + 0]), "v"(pe[8 * sl + 1]));
      asm("v_cvt_pk_bf16_f32 %0, %1, %2" : "=v"(wb) : "v"(pe[8 * sl + 4]), "v"(pe[8 * sl + 5]));
      asm("v_cvt_pk_bf16_f32 %0, %1, %2" : "=v"(wc) : "v"(pe[8 * sl + 2]), "v"(pe[8 * sl + 3]));
      asm("v_cvt_pk_bf16_f32 %0, %1, %2" : "=v"(wd) : "v"(pe[8 * sl + 6]), "v"(pe[8 * sl + 7]));
      asm("v_permlane32_swap_b32 %0, %1" : "+v"(wa), "+v"(wb));
      asm("v_permlane32_swap_b32 %0, %1" : "+v"(wc), "+v"(wd));
      u32x4v t;
      t[0] = wa; t[1] = wc; t[2] = wb; t[3] = wd;
      pa[sl] = __builtin_bit_cast(bf16x8, t);
    }
#pragma unroll
    for (int dt = 0; dt < 2; dt++)
#pragma unroll
      for (int ks = 0; ks < 2; ks++) {
        bf16x8 vf = *(const bf16x8*)&Vbuf[buf][voff[dt][ks]];
        oacc[dt] = MFMA32(pa[ks], vf, oacc[dt]);
      }
  };

  stage(0, 0);
  stage(1, 64);
  for (int kt = 0; kt < 2048; kt += 128) {
    const int p = (kt >> 7) & 1;
    __syncthreads();
    if (kt + 128 < 2048) {
      stage(2 * (p ^ 1), kt + 128);
      stage(2 * (p ^ 1) + 1, kt + 192);
    }
    compute(2 * p);
    compute(2 * p + 1);
  }

  // ---- cross-kg reduction (Kbuf/Vbuf reused as f32 scratch) ----
  __syncthreads();
  float* Ored = (float*)&Kbuf[0][0];  // [4 qg][32 slot][64 lane] f32 = 32KB
  float* Lred = (float*)&Vbuf[0][0];  // [8 wave][64 lane] f32 = 2KB

  float lw = (rs4[0] + rs4[1]) + (rs4[2] + rs4[3]);
  lw += __shfl_xor(lw, 32, 64);
  Lred[wave * 64 + lane] = lw;
  if (kg == 1) {
#pragma unroll
    for (int dt = 0; dt < 2; dt++)
#pragma unroll
      for (int r = 0; r < 16; r++)
        Ored[(qg * 32 + dt * 16 + r) * 64 + lane] = oacc[dt][r];
  }
  __syncthreads();
  if (kg == 0) {
    const int b = bh >> 4, h = bh & 15;
#pragma unroll
    for (int r = 0; r < 16; r++) {
      const int qrow = (r & 3) + 8 * (r >> 2) + 4 * hi;
      const float lt =
          Lred[(qg * 2) * 64 + qrow] + Lred[(qg * 2 + 1) * 64 + qrow];
      const float inv = 1.f / lt;
      const int qAbs = q0 + qg * 32 + qrow;
#pragma unroll
      for (int dt = 0; dt < 2; dt++) {
        const float o = oacc[dt][r] + Ored[(qg * 32 + dt * 16 + r) * 64 + lane];
        Aout[((size_t)(b * 2048 + qAbs)) * 1024 + h * 64 + dt * 32 + l31] =
            (__bf16)(o * inv);
      }
    }
  }
}

extern "C" void kernel_launch(void* const* d_in, const int* in_sizes, int n_in,
                              void* d_out, int out_size, void* d_ws, size_t ws_size,
                              hipStream_t stream) {
  const float* x   = (const float*)d_in[0];
  const float* ctx = (const float*)d_in[1];
  const float* Wq  = (const float*)d_in[2];
  const float* Wv  = (const float*)d_in[3];
  const float* Wo  = (const float*)d_in[4];
  const float* bo  = (const float*)d_in[5];

  char* ws = (char*)d_ws;
  const size_t MB = 1024 * 1024;
  __bf16* xb   = (__bf16*)(ws + 0 * MB);   // [4096,1024]; contiguous with cb
  __bf16* cb   = (__bf16*)(ws + 8 * MB);   // [4096,1024]
  __bf16* Wqb  = (__bf16*)(ws + 16 * MB);  // contiguous with Wvb
  __bf16* Wvb  = (__bf16*)(ws + 18 * MB);
  __bf16* Wob  = (__bf16*)(ws + 20 * MB);
  __bf16* qh   = (__bf16*)(ws + 22 * MB);  // [b,h,s,d], pre-scaled by 0.18034
  __bf16* kh   = (__bf16*)(ws + 30 * MB);  // [b,h,s,d]
  __bf16* vt   = (__bf16*)(ws + 38 * MB);  // [b,h,d,s]
  __bf16* attn = xb;  // xb dead after QK projection

  cvt_all_kernel<<<5632, 256, 0, stream>>>(x, ctx, Wq, Wv, Wo, xb, cb, Wqb, Wvb, Wob);

  gemm_proj<<<192, 512, 0, stream>>>(xb, Wqb, (void*)qh, (void*)kh, (void*)vt);

  attn_kernel<<<512, 512, 0, stream>>>(qh, kh, vt, attn);

  gemm_out<<<128, 512, 0, stream>>>(attn, Wob, (float*)d_out, bo);
}

// Round 10
// 197.161 us; speedup vs baseline: 1.1833x; 1.0198x over previous
//
#include <hip/hip_runtime.h>
#include <cmath>

// MultimodalCrossAttention on MI355X (gfx950), bf16 MFMA pipeline.
// B=2, Sx=Sc=2048, D_MODEL=1024, H=16, hd=64.

typedef __bf16 bf16x8 __attribute__((ext_vector_type(8)));
typedef __bf16 bf16x4 __attribute__((ext_vector_type(4)));
typedef float f32x4 __attribute__((ext_vector_type(4)));
typedef float f32x16 __attribute__((ext_vector_type(16)));
typedef unsigned u32x4v __attribute__((ext_vector_type(4)));

#define MFMA(A, B, C) __builtin_amdgcn_mfma_f32_16x16x32_bf16(A, B, C, 0, 0, 0)
#define MFMA32(A, B, C) __builtin_amdgcn_mfma_f32_32x32x16_bf16(A, B, C, 0, 0, 0)
#define GLL16(g, l)                                                        \
  __builtin_amdgcn_global_load_lds(                                        \
      (const __attribute__((address_space(1))) unsigned int*)(g),          \
      (__attribute__((address_space(3))) unsigned int*)(l), 16, 0, 0)

#define VMCNT(N) asm volatile("s_waitcnt vmcnt(" #N ")" ::: "memory")
#define BARM() asm volatile("s_barrier" ::: "memory")
#define LGKM0() asm volatile("s_waitcnt lgkmcnt(0)" ::: "memory")

// ---------------- fused fp32 -> bf16 convert, 2 float4/thread ----------------
__global__ __launch_bounds__(256) void cvt_all_kernel(
    const float* __restrict__ x, const float* __restrict__ ctx,
    const float* __restrict__ Wq, const float* __restrict__ Wv,
    const float* __restrict__ Wo, __bf16* __restrict__ xb, __bf16* __restrict__ cb,
    __bf16* __restrict__ Wqb, __bf16* __restrict__ Wvb, __bf16* __restrict__ Wob) {
  int base = blockIdx.x * 512 + threadIdx.x;
  const float* src;
  __bf16* dst;
  int off;
  if (base < 1048576) { src = x; dst = xb; off = 0; }
  else if (base < 2097152) { src = ctx; dst = cb; off = 1048576; }
  else if (base < 2359296) { src = Wq; dst = Wqb; off = 2097152; }
  else if (base < 2621440) { src = Wv; dst = Wvb; off = 2359296; }
  else { src = Wo; dst = Wob; off = 2621440; }
#pragma unroll
  for (int jj = 0; jj < 2; jj++) {
    int j = base - off + jj * 256;
    float4 f = ((const float4*)src)[j];
    bf16x4 o;
    o[0] = (__bf16)f.x; o[1] = (__bf16)f.y; o[2] = (__bf16)f.z; o[3] = (__bf16)f.w;
    ((bf16x4*)dst)[j] = o;
  }
}

// ---------------- Projection GEMM: 256x256, 8-phase schedule (proven round 6) ----------------
// vmode epilogue changed: V written in k-chunked layout V''[bh][s/8][d][8]
// (elem (s,d) at (s>>3)*512 + d*8 + (s&7)) so attn's per-lane V fragment loads
// are 16B-stride coalesced straight from global (R8 path done right).
__global__ __launch_bounds__(512, 2) void gemm_proj(const __bf16* __restrict__ A0,
                                                    const __bf16* __restrict__ W0,
                                                    void* __restrict__ outQ,
                                                    void* __restrict__ outK,
                                                    void* __restrict__ outV) {
  const int tid = threadIdx.x;
  const int wave = tid >> 6, lane = tid & 63, quad = lane >> 4, l15 = lane & 15;
  const int wm = wave >> 2, wn = wave & 3;

  const int id = blockIdx.x;
  int m0, n0;
  const __bf16* A;
  const __bf16* W;
  bool vmode;
  if (id < 128) {                        // QK: A = xb||cb (8192 rows), W = Wq
    const int xcd = id & 7, j = id >> 3; // j 0..15
    m0 = (xcd * 4 + (j & 3)) * 256;
    n0 = (j >> 2) * 256;
    A = A0;
    W = W0;
    vmode = false;
  } else {                               // V: A = cb (4096 rows), W = Wv
    const int vid = id - 128;
    const int xcd = vid & 7, j = vid >> 3;  // j 0..7
    m0 = (xcd * 2 + (j & 1)) * 256;
    n0 = (j >> 1) * 256;
    A = A0 + (size_t)4096 * 1024;
    W = W0 + (size_t)1024 * 1024;
    vmode = true;
  }

  __shared__ __attribute__((aligned(16))) __bf16 As[2][2][8192];  // 64KB
  __shared__ __attribute__((aligned(16))) __bf16 Bs[2][2][8192];  // 64KB

  const int srow = tid >> 2;
  const int kcg = (tid & 3) ^ (srow & 3);
  const size_t aoff0 = (size_t)srow * 1024 + kcg * 8;
  const size_t aoff1 = (size_t)(srow + 128) * 1024 + kcg * 8;
  const __bf16* Ag = A + (size_t)m0 * 1024;
  const __bf16* Wg = W + (size_t)n0 * 1024;
  const int ldst0 = wave * 512;
  const int ldst1 = 4096 + wave * 512;

  auto stageA = [&](int slot, int kh, int kel) {
    GLL16(Ag + aoff0 + kel, &As[slot][kh][ldst0]);
    GLL16(Ag + aoff1 + kel, &As[slot][kh][ldst1]);
  };
  auto stageB = [&](int slot, int kh, int kel) {
    GLL16(Wg + aoff0 + kel, &Bs[slot][kh][ldst0]);
    GLL16(Wg + aoff1 + kel, &Bs[slot][kh][ldst1]);
  };

  const int xk = (quad ^ (l15 & 3)) * 8;
  int afo[8], bfo[4];
#pragma unroll
  for (int mf = 0; mf < 8; mf++) afo[mf] = (wm * 128 + mf * 16 + l15) * 32 + xk;
#pragma unroll
  for (int nf = 0; nf < 4; nf++) bfo[nf] = (wn * 64 + nf * 16 + l15) * 32 + xk;

  f32x4 acc[8][4] = {};
  bf16x8 bf[4], af[4];

  auto loadB = [&](int slot, int kh) {
#pragma unroll
    for (int nf = 0; nf < 4; nf++) bf[nf] = *(const bf16x8*)&Bs[slot][kh][bfo[nf]];
  };
  auto loadA = [&](int slot, int kh, int mfg) {
#pragma unroll
    for (int mf = 0; mf < 4; mf++)
      af[mf] = *(const bf16x8*)&As[slot][kh][afo[mfg * 4 + mf]];
  };
  auto mfma16 = [&](int mfg) {
    __builtin_amdgcn_s_setprio(1);
#pragma unroll
    for (int mf = 0; mf < 4; mf++)
#pragma unroll
      for (int nf = 0; nf < 4; nf++)
        acc[mfg * 4 + mf][nf] = MFMA(af[mf], bf[nf], acc[mfg * 4 + mf][nf]);
    __builtin_amdgcn_s_setprio(0);
  };

  stageA(0, 0, 0);  stageB(0, 0, 0);
  stageA(0, 1, 32); stageB(0, 1, 32);
  stageA(1, 0, 64); stageB(1, 0, 64);
  VMCNT(8); BARM();

#pragma unroll 1
  for (int j = 0; j < 7; j++) {
    const int kb = j * 128;
    loadB(0, 0); loadA(0, 0, 0); stageA(1, 1, kb + 96);
    BARM(); LGKM0(); mfma16(0); BARM();
    loadA(0, 0, 1); stageB(1, 1, kb + 96);
    BARM(); LGKM0(); mfma16(1); VMCNT(8); BARM();
    loadB(0, 1); loadA(0, 1, 0); stageA(0, 0, kb + 128);
    BARM(); LGKM0(); mfma16(0); BARM();
    loadA(0, 1, 1); stageB(0, 0, kb + 128);
    BARM(); LGKM0(); mfma16(1); VMCNT(8); BARM();
    loadB(1, 0); loadA(1, 0, 0); stageA(0, 1, kb + 160);
    BARM(); LGKM0(); mfma16(0); BARM();
    loadA(1, 0, 1); stageB(0, 1, kb + 160);
    BARM(); LGKM0(); mfma16(1); VMCNT(8); BARM();
    loadB(1, 1); loadA(1, 1, 0); stageA(1, 0, kb + 192);
    BARM(); LGKM0(); mfma16(0); BARM();
    loadA(1, 1, 1); stageB(1, 0, kb + 192);
    BARM(); LGKM0(); mfma16(1); VMCNT(8); BARM();
  }
  {
    loadB(0, 0); loadA(0, 0, 0); stageA(1, 1, 992);
    BARM(); LGKM0(); mfma16(0); BARM();
    loadA(0, 0, 1); stageB(1, 1, 992);
    BARM(); LGKM0(); mfma16(1); VMCNT(8); BARM();
    loadB(0, 1); loadA(0, 1, 0);
    BARM(); LGKM0(); mfma16(0); BARM();
    loadA(0, 1, 1);
    BARM(); LGKM0(); mfma16(1); VMCNT(4); BARM();
    loadB(1, 0); loadA(1, 0, 0);
    BARM(); LGKM0(); mfma16(0); BARM();
    loadA(1, 0, 1);
    BARM(); LGKM0(); mfma16(1); VMCNT(0); BARM();
    loadB(1, 1); loadA(1, 1, 0);
    BARM(); LGKM0(); mfma16(0); BARM();
    loadA(1, 1, 1);
    BARM(); LGKM0(); mfma16(1);
  }

  if (!vmode) {
    const int isK = (m0 >= 4096);
    __bf16* O = (__bf16*)(isK ? outK : outQ);
    const float qsc = isK ? 1.0f : 0.18033688f;  // 0.125*log2(e) folded into Q
    const int mb = m0 & 4095;
#pragma unroll
    for (int nf = 0; nf < 4; nf++) {
      const int n = n0 + wn * 64 + nf * 16 + l15;
      const int h = n >> 6, d = n & 63, p = d >> 1;
      const float invf_rev =
          __builtin_amdgcn_exp2f(-((float)p * 0.41524101f + 2.6514961f));
#pragma unroll
      for (int mf = 0; mf < 8; mf++) {
#pragma unroll
        for (int r = 0; r < 4; r++) {
          const int row = mb + wm * 128 + mf * 16 + quad * 4 + r;
          const int s = row & 2047, b = row >> 11;
          float v = acc[mf][nf][r];
          float pv = __shfl_xor(v, 1, 64);
          float fr = __builtin_amdgcn_fractf((float)s * invf_rev);
          float sn = __builtin_amdgcn_sinf(fr);
          float cs = __builtin_amdgcn_cosf(fr);
          float res = (lane & 1) ? (pv * sn + v * cs) : (v * cs - pv * sn);
          O[((size_t)(b * 16 + h) * 2048 + s) * 64 + d] = (__bf16)(res * qsc);
        }
      }
    }
  } else {
    // V'' chunk layout: plane = (b*16+h)*131072; elem (s,d) at (s>>3)*512 + d*8 + (s&7)
    __bf16* O = (__bf16*)outV;
#pragma unroll
    for (int nf = 0; nf < 4; nf++) {
      const int n = n0 + wn * 64 + nf * 16 + l15;
      const int h = n >> 6, d = n & 63;
#pragma unroll
      for (int mf = 0; mf < 8; mf++) {
        const int rowb = m0 + wm * 128 + mf * 16 + quad * 4;
        const int s = rowb & 2047, b = rowb >> 11;
        bf16x4 o;
#pragma unroll
        for (int r = 0; r < 4; r++) o[r] = (__bf16)acc[mf][nf][r];
        *(bf16x4*)(O + (size_t)(b * 16 + h) * 131072 + (size_t)(s >> 3) * 512 +
                   d * 8 + (s & 7)) = o;
      }
    }
  }
}

// ---------------- Out-proj GEMM: 128x64 tile, triple-buffered, XCD-swizzled ----------------
// (round-2 proven version; R9 showed the 8-phase/grid-128 variant was ~3us worse)
__global__ __launch_bounds__(256) void gemm_out(const __bf16* __restrict__ A,
                                                const __bf16* __restrict__ W,
                                                float* __restrict__ O,
                                                const float* __restrict__ bias) {
  const int tid = threadIdx.x;
  const int wave = tid >> 6, lane = tid & 63, quad = lane >> 4, l15 = lane & 15;
  const int mw = wave >> 1, nw = wave & 1;
  const int id = blockIdx.x;
  const int xcd = id & 7, j = id >> 3;       // j 0..63
  const int m0 = (xcd * 4 + (j & 3)) * 128;  // 32 m-tiles
  const int n0 = (j >> 2) * 64;              // 16 n-tiles

  __shared__ __attribute__((aligned(16))) __bf16 As[3][4096];  // 24KB
  __shared__ __attribute__((aligned(16))) __bf16 Ws[3][2048];  // 12KB

  int goff[2];
#pragma unroll
  for (int jj = 0; jj < 2; jj++) {
    const int s = jj * 256 + tid;
    const int row = s >> 2;
    const int kcg = (s & 3) ^ ((row >> 1) & 3);
    goff[jj] = row * 1024 + kcg * 8;
  }
  const int wrow = tid >> 2;
  const int wkcg = (tid & 3) ^ ((wrow >> 1) & 3);
  const int goffw = wrow * 1024 + wkcg * 8;

  const __bf16* Ag = A + (size_t)m0 * 1024;
  const __bf16* Wg = W + (size_t)n0 * 1024;
  const int ldsoff0 = wave * 512;
  const int ldsoff1 = 2048 + wave * 512;

  const int sw = (l15 >> 1) & 3;
  int afoff[4], wfoff[2];
#pragma unroll
  for (int t = 0; t < 4; t++)
    afoff[t] = (mw * 64 + t * 16 + l15) * 32 + (quad ^ sw) * 8;
#pragma unroll
  for (int t = 0; t < 2; t++)
    wfoff[t] = (nw * 32 + t * 16 + l15) * 32 + (quad ^ sw) * 8;

  f32x4 acc[4][2] = {};

  auto stage = [&](int buf, int k0) {
    GLL16(Ag + goff[0] + k0, &As[buf][ldsoff0]);
    GLL16(Ag + goff[1] + k0, &As[buf][ldsoff1]);
    GLL16(Wg + goffw + k0, &Ws[buf][ldsoff0]);
  };
  auto compute = [&](int buf) {
    bf16x8 af[4], wf[2];
#pragma unroll
    for (int t = 0; t < 4; t++) af[t] = *(const bf16x8*)&As[buf][afoff[t]];
#pragma unroll
    for (int t = 0; t < 2; t++) wf[t] = *(const bf16x8*)&Ws[buf][wfoff[t]];
#pragma unroll
    for (int mt = 0; mt < 4; mt++)
#pragma unroll
      for (int nt = 0; nt < 2; nt++) acc[mt][nt] = MFMA(af[mt], wf[nt], acc[mt][nt]);
  };

  stage(0, 0);
  stage(1, 32);
  int buf = 0;
  for (int c = 0; c < 32; c++) {
    __syncthreads();
    if (c + 2 < 32) {
      int nb = buf + 2;
      if (nb >= 3) nb -= 3;
      stage(nb, (c + 2) * 32);
    }
    compute(buf);
    buf = (buf == 2) ? 0 : buf + 1;
  }

#pragma unroll
  for (int nt = 0; nt < 2; nt++) {
    const int n = n0 + nw * 32 + nt * 16 + l15;
    const float bv = bias[n];
#pragma unroll
    for (int mt = 0; mt < 4; mt++) {
#pragma unroll
      for (int r = 0; r < 4; r++) {
        const int row = m0 + mw * 64 + mt * 16 + quad * 4 + r;
        O[(size_t)row * 1024 + n] = acc[mt][nt][r] + bv;
      }
    }
  }
}

// ---------------- Flash attention: K via LDS (proven R6 path), V global->reg coalesced ----------------
// K staging/reads identical to the proven 49.5us kernel. V comes straight from
// the chunked V'' layout into registers (16B/lane coalesced), ping-ponged one
// half-tile ahead (T14). No Vbuf: LDS reads per wave-compute 8 -> 4; LDS 34KB.
__global__ __launch_bounds__(512, 4) void attn_kernel(const __bf16* __restrict__ Q,
                                                      const __bf16* __restrict__ K,
                                                      const __bf16* __restrict__ Vt,
                                                      __bf16* __restrict__ Aout) {
  const int tid = threadIdx.x;
  const int wave = tid >> 6, lane = tid & 63;
  const int l31 = lane & 31, hi = lane >> 5;
  const int qg = wave >> 1, kg = wave & 1;
  const int id = blockIdx.x;
  const int j = id >> 3;
  const int bh = ((id & 7) << 2) | (j & 3);
  const int q0 = (j >> 2) << 7;

  const __bf16* Qb = Q + (size_t)bh * (2048 * 64);
  const __bf16* Kb = K + (size_t)bh * (2048 * 64);
  const __bf16* Vb = Vt + (size_t)bh * 131072;  // V'' chunk layout

  __shared__ __attribute__((aligned(16))) __bf16 Kbuf[4][4096];  // 32KB
  __shared__ __attribute__((aligned(16))) float Lred[512];       // 2KB

  bf16x8 qf[4];
  {
    const __bf16* qp = Qb + (size_t)(q0 + qg * 32 + l31) * 64 + hi * 8;
#pragma unroll
    for (int i = 0; i < 4; i++) qf[i] = *(const bf16x8*)(qp + i * 16);
  }

  // K staging (proven): row-major with 8-col XOR swizzle
  const int s0 = wave * 64 + lane;
  const int r0 = s0 >> 3, c0 = (s0 & 7) ^ (r0 & 7);
  const __bf16* kgp = Kb + r0 * 64 + c0 * 8;
  const int klds = wave * 512;

  int koff[4];
  {
    const int rk = kg * 32 + l31;
#pragma unroll
    for (int i = 0; i < 4; i++) koff[i] = rk * 64 + (((2 * i + hi) ^ (rk & 7)) * 8);
  }

  // V frag from global: vf[dt][ks][j] = V[ktc + (kg*4+ks*2+hi)*8 + j][dt*32+l31]
  // = Vb + ((ktc>>3)+kg*4+ks*2+hi)*512 + (dt*32+l31)*8 + j   (16B/lane, coalesced)
  const int vchunk = (kg * 4 + hi) * 512;
  const int vdoff = l31 * 8;

  f32x4 rs4 = {};
  f32x16 oacc[2] = {};

  auto stageK = [&](int buf, int kt) { GLL16(kgp + kt * 64, &Kbuf[buf][klds]); };

  auto loadV = [&](bf16x8 (&vf)[2][2], int ktc) {
#pragma unroll
    for (int dt = 0; dt < 2; dt++)
#pragma unroll
      for (int ks = 0; ks < 2; ks++)
        vf[dt][ks] = *(const bf16x8*)(Vb + (size_t)((ktc >> 3) + ks * 2) * 512 +
                                      vchunk + dt * 32 * 8 + vdoff);
  };

  auto compute = [&](int buf, const bf16x8 (&vf)[2][2]) {
    f32x16 s = {};
#pragma unroll
    for (int i = 0; i < 4; i++) {
      bf16x8 kf = *(const bf16x8*)&Kbuf[buf][koff[i]];
      s = MFMA32(kf, qf[i], s);
    }
    float pe[16];
#pragma unroll
    for (int r = 0; r < 16; r++) pe[r] = __builtin_amdgcn_exp2f(s[r]);
#pragma unroll
    for (int r = 0; r < 16; r++) rs4[r & 3] += pe[r];
    bf16x8 pa[2];
#pragma unroll
    for (int sl = 0; sl < 2; sl++) {
      unsigned wa, wb, wc, wd;
      asm("v_cvt_pk_bf16_f32 %0, %1, %2" : "=v"(wa) : "v"(pe[8 * sl + 0]), "v"(pe[8 * sl + 1]));
      asm("v_cvt_pk_bf16_f32 %0, %1, %2" : "=v"(wb) : "v"(pe[8 * sl + 4]), "v"(pe[8 * sl + 5]));
      asm("v_cvt_pk_bf16_f32 %0, %1, %2" : "=v"(wc) : "v"(pe[8 * sl + 2]), "v"(pe[8 * sl + 3]));
      asm("v_cvt_pk_bf16_f32 %0, %1, %2" : "=v"(wd) : "v"(pe[8 * sl + 6]), "v"(pe[8 * sl + 7]));
      asm("v_permlane32_swap_b32 %0, %1" : "+v"(wa), "+v"(wb));
      asm("v_permlane32_swap_b32 %0, %1" : "+v"(wc), "+v"(wd));
      u32x4v t;
      t[0] = wa; t[1] = wc; t[2] = wb; t[3] = wd;
      pa[sl] = __builtin_bit_cast(bf16x8, t);
    }
#pragma unroll
    for (int dt = 0; dt < 2; dt++)
#pragma unroll
      for (int ks = 0; ks < 2; ks++)
        oacc[dt] = MFMA32(pa[ks], vf[dt][ks], oacc[dt]);
  };

  bf16x8 vX[2][2], vY[2][2];
  loadV(vX, 0);
  stageK(0, 0);
  stageK(1, 64);
  for (int kt = 0; kt < 2048; kt += 128) {
    const int p = (kt >> 7) & 1;
    __syncthreads();
    if (kt + 128 < 2048) {
      stageK(2 * (p ^ 1), kt + 128);
      stageK(2 * (p ^ 1) + 1, kt + 192);
    }
    loadV(vY, kt + 64);
    compute(2 * p, vX);
    if (kt + 128 < 2048) loadV(vX, kt + 128);
    compute(2 * p + 1, vY);
  }

  // ---- cross-kg reduction (Kbuf reused as f32 scratch) ----
  __syncthreads();
  float* Ored = (float*)&Kbuf[0][0];  // [4 qg][32 slot][64 lane] f32 = 32KB

  float lw = (rs4[0] + rs4[1]) + (rs4[2] + rs4[3]);
  lw += __shfl_xor(lw, 32, 64);
  Lred[wave * 64 + lane] = lw;
  if (kg == 1) {
#pragma unroll
    for (int dt = 0; dt < 2; dt++)
#pragma unroll
      for (int r = 0; r < 16; r++)
        Ored[(qg * 32 + dt * 16 + r) * 64 + lane] = oacc[dt][r];
  }
  __syncthreads();
  if (kg == 0) {
    const int b = bh >> 4, h = bh & 15;
#pragma unroll
    for (int r = 0; r < 16; r++) {
      const int qrow = (r & 3) + 8 * (r >> 2) + 4 * hi;
      const float lt =
          Lred[(qg * 2) * 64 + qrow] + Lred[(qg * 2 + 1) * 64 + qrow];
      const float inv = 1.f / lt;
      const int qAbs = q0 + qg * 32 + qrow;
#pragma unroll
      for (int dt = 0; dt < 2; dt++) {
        const float o = oacc[dt][r] + Ored[(qg * 32 + dt * 16 + r) * 64 + lane];
        Aout[((size_t)(b * 2048 + qAbs)) * 1024 + h * 64 + dt * 32 + l31] =
            (__bf16)(o * inv);
      }
    }
  }
}

extern "C" void kernel_launch(void* const* d_in, const int* in_sizes, int n_in,
                              void* d_out, int out_size, void* d_ws, size_t ws_size,
                              hipStream_t stream) {
  const float* x   = (const float*)d_in[0];
  const float* ctx = (const float*)d_in[1];
  const float* Wq  = (const float*)d_in[2];
  const float* Wv  = (const float*)d_in[3];
  const float* Wo  = (const float*)d_in[4];
  const float* bo  = (const float*)d_in[5];

  char* ws = (char*)d_ws;
  const size_t MB = 1024 * 1024;
  __bf16* xb   = (__bf16*)(ws + 0 * MB);   // [4096,1024]; contiguous with cb
  __bf16* cb   = (__bf16*)(ws + 8 * MB);   // [4096,1024]
  __bf16* Wqb  = (__bf16*)(ws + 16 * MB);  // contiguous with Wvb
  __bf16* Wvb  = (__bf16*)(ws + 18 * MB);
  __bf16* Wob  = (__bf16*)(ws + 20 * MB);
  __bf16* qh   = (__bf16*)(ws + 22 * MB);  // [b,h,s,d], pre-scaled by 0.18034
  __bf16* kh   = (__bf16*)(ws + 30 * MB);  // [b,h,s,d]
  __bf16* vt   = (__bf16*)(ws + 38 * MB);  // V'' chunk layout [bh][s/8][d][8]
  __bf16* attn = xb;  // xb dead after QK projection

  cvt_all_kernel<<<5632, 256, 0, stream>>>(x, ctx, Wq, Wv, Wo, xb, cb, Wqb, Wvb, Wob);

  gemm_proj<<<192, 512, 0, stream>>>(xb, Wqb, (void*)qh, (void*)kh, (void*)vt);

  attn_kernel<<<512, 512, 0, stream>>>(qh, kh, vt, attn);

  gemm_out<<<512, 256, 0, stream>>>(attn, Wob, (float*)d_out, bo);
}